// Round 3
// baseline (394.676 us; speedup 1.0000x reference)
//
#include <hip/hip_runtime.h>

#define NQ    2000      // B*L
#define KDIM  8192      // G*P*ch = 4*32*64
#define EMB   256
#define MPAD  2048      // NQ padded for GEMM tiles
#define SPLITK 8

typedef __attribute__((ext_vector_type(8))) short bf16x8;
typedef __attribute__((ext_vector_type(4))) float f32x4;

__device__ __forceinline__ float sigf(float x) { return 1.0f / (1.0f + __expf(-x)); }

__device__ __forceinline__ unsigned short f2bf(float x) {
    union { float f; unsigned int u; } v; v.f = x;
    unsigned int r = v.u + 0x7fffu + ((v.u >> 16) & 1u);
    return (unsigned short)(r >> 16);
}
__device__ __forceinline__ float bf2f(unsigned short h) {
    union { unsigned int u; float f; } v; v.u = ((unsigned int)h) << 16; return v.f;
}

// ---------------------------------------------------------------------------
// Kernel T (merged): all one-time layout work in a single launch.
//   region A [0,2720): BCHW fp32 -> BHWC bf16 transpose, 4 levels.
//     Block = 64 channels x 256 px. Read: one wave-instr = float4 x 64 lanes
//     = 1 KB CONTIGUOUS from one channel row (segment-size experiment: DRAM/
//     fabric efficiency theory says 128-256B strided segments are the 2 TB/s
//     wall). LDS [64ch][256px] fp32 (64 KB, 2 blk/CU). Store: thread = px,
//     8x uint4 = 128 B contiguous per px at 512 B stride (full lines only).
//   region B [2720,4768):   Wout(8192,256) -> Wtb(256,8192) bf16
//   region C [4768,5280):   {Woff|Wca1|Wsa1} -> WH/WL (512,256) double-bf16
//   region D [5280,7328):   qc -> qcH/qcL (2048,256) double-bf16, zero-pad
// ---------------------------------------------------------------------------
__global__ __launch_bounds__(256) void trans_kernel(
    const float* __restrict__ v0, const float* __restrict__ v1,
    const float* __restrict__ v2, const float* __restrict__ v3,
    unsigned short* __restrict__ vt0, unsigned short* __restrict__ vt1,
    unsigned short* __restrict__ vt2, unsigned short* __restrict__ vt3,
    const float* __restrict__ Wout, unsigned short* __restrict__ Wtb,
    const float* __restrict__ Woff, const float* __restrict__ Wca1,
    const float* __restrict__ Wsa1,
    unsigned short* __restrict__ WH, unsigned short* __restrict__ WL,
    const float* __restrict__ qc,
    unsigned short* __restrict__ qcH, unsigned short* __restrict__ qcL)
{
    __shared__ float ldsbuf[64 * 256];   // 64 KB; region A tile [ch][px]
    int bid = blockIdx.x;
    const int t = threadIdx.x;

    if (bid < 2720) {
        // -------- region A: value transpose --------
        const float* v; unsigned short* vt; int HW, b, strip, chq;
        if (bid < 2048) {
            v = v0; vt = vt0; HW = 65536;
            b = bid >> 10; const int rem = bid & 1023; strip = rem >> 2; chq = rem & 3;
        } else if (bid < 2560) {
            const int local = bid - 2048; v = v1; vt = vt1; HW = 16384;
            b = local >> 8; const int rem = local & 255; strip = rem >> 2; chq = rem & 3;
        } else if (bid < 2688) {
            const int local = bid - 2560; v = v2; vt = vt2; HW = 4096;
            b = local >> 6; const int rem = local & 63; strip = rem >> 2; chq = rem & 3;
        } else {
            const int local = bid - 2688; v = v3; vt = vt3; HW = 1024;
            b = local >> 4; const int rem = local & 15; strip = rem >> 2; chq = rem & 3;
        }
        const int px0 = strip << 8;     // 256-px strip base
        const int cq0 = chq << 6;       // 64-ch quadrant base

        const int w    = t >> 6;        // wave 0..3
        const int lane = t & 63;

        // read: 16 x (1 KB contiguous wave-segment), one channel row each
        const float* vb = v + ((size_t)(b * 256 + cq0)) * HW + px0;
        float4 st[16];
        #pragma unroll
        for (int i = 0; i < 16; i++)
            st[i] = *(const float4*)(vb + (size_t)(w * 16 + i) * HW + 4 * lane);

        // stage: LDS [c][256], b128 writes (lanes tile all 32 banks evenly)
        #pragma unroll
        for (int i = 0; i < 16; i++)
            *(float4*)&ldsbuf[(w * 16 + i) * 256 + 4 * lane] = st[i];
        __syncthreads();

        // store: thread = px; 64 ch -> 8 x uint4 = 128 B contiguous
        unsigned short* ob = vt + ((size_t)b * HW + px0 + t) * 256 + cq0;
        #pragma unroll
        for (int j = 0; j < 8; j++) {
            float f[8];
            #pragma unroll
            for (int m = 0; m < 8; m++)
                f[m] = ldsbuf[(j * 8 + m) * 256 + t];   // bank = t%32, 2-way = free
            uint4 o;
            o.x = (unsigned int)f2bf(f[0]) | ((unsigned int)f2bf(f[1]) << 16);
            o.y = (unsigned int)f2bf(f[2]) | ((unsigned int)f2bf(f[3]) << 16);
            o.z = (unsigned int)f2bf(f[4]) | ((unsigned int)f2bf(f[5]) << 16);
            o.w = (unsigned int)f2bf(f[6]) | ((unsigned int)f2bf(f[7]) << 16);
            *(uint4*)(ob + j * 8) = o;
        }
    } else if (bid < 4768) {
        // -------- region B: Wout transpose --------
        const int local = bid - 2720;
        const int k0 = (local & 255) * 32, n0 = (local >> 8) * 32;
        float (*tl)[33] = (float(*)[33])ldsbuf;
        #pragma unroll
        for (int i = 0; i < 4; i++) {
            const int ki = (t >> 5) + i * 8;
            tl[ki][t & 31] = Wout[(size_t)(k0 + ki) * 256 + n0 + (t & 31)];
        }
        __syncthreads();
        #pragma unroll
        for (int i = 0; i < 4; i++) {
            const int ni = (t >> 5) + i * 8;
            const int ki = t & 31;
            Wtb[(size_t)(n0 + ni) * KDIM + k0 + ki] = f2bf(tl[ki][ni]);
        }
    } else if (bid < 5280) {
        // -------- region C: small weights, double-bf16 --------
        const int n = bid - 4768;         // 0..511, thread = k
        float val;
        if (n < 384)      val = Woff[(size_t)t * 384 + n];
        else if (n < 448) val = Wca1[(size_t)t * 64 + (n - 384)];
        else              val = Wsa1[(size_t)t * 64 + (n - 448)];
        const unsigned short hh = f2bf(val);
        WH[(size_t)n * 256 + t] = hh;
        WL[(size_t)n * 256 + t] = f2bf(val - bf2f(hh));
    } else {
        // -------- region D: qc double-bf16, zero-pad --------
        const int q = bid - 5280;         // 0..2047
        const float val = (q < NQ) ? qc[(size_t)q * 256 + t] : 0.f;
        const unsigned short hh = f2bf(val);
        qcH[(size_t)q * 256 + t] = hh;
        qcL[(size_t)q * 256 + t] = f2bf(val - bf2f(hh));
    }
}

// ---------------------------------------------------------------------------
// Kernel A: H(2048,512) = qc(2048,256) @ [Woff|Wca1|Wsa1](256,512), fp32-ish
// accuracy via double-bf16 (3 MFMA passes: AH*BH + AH*BL + AL*BH).
// No LDS; fragments loaded directly from global (K-contiguous both sides).
// grid (32, 8), 256 thr = 4 waves, wave = 32x32 quadrant (2x2 of 16x16x32).
// ---------------------------------------------------------------------------
__global__ __launch_bounds__(256) void gemmA_kernel(
    const unsigned short* __restrict__ qcH, const unsigned short* __restrict__ qcL,
    const unsigned short* __restrict__ WH,  const unsigned short* __restrict__ WL,
    float* __restrict__ Hout)               // (2048, 512)
{
    const int m0 = blockIdx.x * 64;
    const int n0 = blockIdx.y * 64;
    const int t  = threadIdx.x;
    const int w    = t >> 6;
    const int lane = t & 63;
    const int mw = (w & 1) * 32;
    const int nw = (w >> 1) * 32;
    const int quad = lane >> 4;
    const int l16  = lane & 15;

    f32x4 acc[2][2] = {};
    #pragma unroll
    for (int pass = 0; pass < 3; pass++) {
        const unsigned short* Ap = (pass == 2) ? qcL : qcH;
        const unsigned short* Bp = (pass == 1) ? WL : WH;
        const unsigned short* ar0 = Ap + (size_t)(m0 + mw + l16) * 256 + quad * 8;
        const unsigned short* ar1 = ar0 + 16 * 256;
        const unsigned short* br0 = Bp + (size_t)(n0 + nw + l16) * 256 + quad * 8;
        const unsigned short* br1 = br0 + 16 * 256;
        #pragma unroll
        for (int k = 0; k < 256; k += 32) {
            const bf16x8 a0 = *(const bf16x8*)(ar0 + k);
            const bf16x8 a1 = *(const bf16x8*)(ar1 + k);
            const bf16x8 b0 = *(const bf16x8*)(br0 + k);
            const bf16x8 b1 = *(const bf16x8*)(br1 + k);
            acc[0][0] = __builtin_amdgcn_mfma_f32_16x16x32_bf16(a0, b0, acc[0][0], 0, 0, 0);
            acc[0][1] = __builtin_amdgcn_mfma_f32_16x16x32_bf16(a0, b1, acc[0][1], 0, 0, 0);
            acc[1][0] = __builtin_amdgcn_mfma_f32_16x16x32_bf16(a1, b0, acc[1][0], 0, 0, 0);
            acc[1][1] = __builtin_amdgcn_mfma_f32_16x16x32_bf16(a1, b1, acc[1][1], 0, 0, 0);
        }
    }
    #pragma unroll
    for (int i = 0; i < 2; i++)
        #pragma unroll
        for (int j = 0; j < 2; j++) {
            const int n = n0 + nw + 16 * j + l16;
            #pragma unroll
            for (int r = 0; r < 4; r++) {
                const int m = m0 + mw + 16 * i + quad * 4 + r;
                Hout[(size_t)m * 512 + n] = acc[i][j][r];
            }
        }
}

// ---------------------------------------------------------------------------
// Kernel F: finish — per 8-query block: ca/sa second-layer dots + sigmoid +
// sampling geometry. Reads H(2048,512): [0,384)=offsets(+boff here),
// [384,448)=ca hidden (relu), [448,512)=sa hidden (relu).
// qdata per query (1024 f): [0,128) px | [128,256) py | [256,768) w[p][4] |
// [768,1024) ca.
// ---------------------------------------------------------------------------
__global__ __launch_bounds__(256) void finish_kernel(
    const float* __restrict__ Hbuf, const float* __restrict__ xyzrt,
    const float* __restrict__ boff,
    const float* __restrict__ Wca2, const float* __restrict__ Wsa2,
    float* __restrict__ qdata)
{
    const int q0 = blockIdx.x * 8;
    const int t  = threadIdx.x;
    __shared__ float hca[8][64];
    __shared__ float hsa[8][64];
    __shared__ float sas[8][128];

    for (int i = t; i < 1024; i += 256) {
        const int q = i >> 7, j = i & 127;
        const float v = fmaxf(Hbuf[(size_t)(q0 + q) * 512 + 384 + j], 0.f);
        if (j < 64) hca[q][j] = v; else hsa[q][j - 64] = v;
    }
    __syncthreads();

    {   // ca: channel c = t, all 8 queries
        float acc[8] = {};
        for (int j = 0; j < 64; j++) {
            const float wv = Wca2[(size_t)j * 256 + t];
            #pragma unroll
            for (int q = 0; q < 8; q++) acc[q] = fmaf(hca[q][j], wv, acc[q]);
        }
        #pragma unroll
        for (int q = 0; q < 8; q++)
            qdata[(size_t)(q0 + q) * 1024 + 768 + t] = sigf(acc[q]);
    }
    {   // sa: c = t&127, 4 queries per thread
        const int c  = t & 127;
        const int qb = (t >> 7) * 4;
        float acc[4] = {};
        for (int j = 0; j < 64; j++) {
            const float wv = Wsa2[(size_t)j * 128 + c];
            #pragma unroll
            for (int qq = 0; qq < 4; qq++) acc[qq] = fmaf(hsa[qb + qq][j], wv, acc[qq]);
        }
        #pragma unroll
        for (int qq = 0; qq < 4; qq++) sas[qb + qq][c] = sigf(acc[qq]);
    }
    __syncthreads();

    {   // geometry: p = t&127, 4 queries per thread
        const int p  = t & 127;
        const int qb = (t >> 7) * 4;
        #pragma unroll
        for (int qq = 0; qq < 4; qq++) {
            const int q = qb + qq;
            const float* hrow = Hbuf + (size_t)(q0 + q) * 512 + p * 3;
            const float o0 = hrow[0] + boff[p * 3 + 0];
            const float o1 = hrow[1] + boff[p * 3 + 1];
            const float o2 = hrow[2] + boff[p * 3 + 2];
            const float* xr = xyzrt + (size_t)(q0 + q) * 5;
            const float x = xr[0], y = xr[1], z = xr[2], r = xr[3], th = xr[4];
            const float sc  = exp2f(z);
            const float rw  = sc * exp2f(-0.5f * r);
            const float rh  = sc * exp2f( 0.5f * r);
            const float cth = __cosf(th), sth = __sinf(th);
            const float ox = o0 * rw;
            const float oy = o1 * rh;
            float* qd = qdata + (size_t)(q0 + q) * 1024;
            qd[p]       = x + cth * ox - sth * oy;
            qd[128 + p] = y + sth * ox + cth * oy;
            const float sz = z + o2;
            const float sa = sas[q][p];
            #pragma unroll
            for (int l = 0; l < 4; l++) {
                const float d = sz - (float)(2 + l);
                qd[256 + p * 4 + l] = sigf(-0.5f * d * d) * sa;
            }
        }
    }
}

// ---------------------------------------------------------------------------
// Kernel 2: vectorized multi-level bilinear sampling from BHWC bf16.
// One wave = 8 points x 64 ch; lane = (pt = lane>>3, c8 = (lane&7)*8).
// ---------------------------------------------------------------------------
__global__ __launch_bounds__(256) void sample_kernel(
    const unsigned short* __restrict__ v0, const unsigned short* __restrict__ v1,
    const unsigned short* __restrict__ v2, const unsigned short* __restrict__ v3,
    const float* __restrict__ qdata,
    unsigned short* __restrict__ X)
{
    const int wid  = blockIdx.x * 4 + (threadIdx.x >> 6);
    const int lane = threadIdx.x & 63;
    const int q  = wid >> 4;
    const int pb = (wid & 15) * 8;
    const int pt = lane >> 3;
    const int gp = pb + pt;
    const int g  = gp >> 5;
    const int c8 = (lane & 7) * 8;
    const int b  = (q >= 1000) ? 1 : 0;

    const float* qd = qdata + (size_t)q * 1024;
    const float px = qd[gp];
    const float py = qd[128 + gp];
    float wlv[4];
    #pragma unroll
    for (int l = 0; l < 4; l++) wlv[l] = qd[256 + gp * 4 + l];

    const unsigned short* vals[4] = { v0, v1, v2, v3 };
    const int cbase = g * 64 + c8;

    float acc[8] = {};
    #pragma unroll
    for (int l = 0; l < 4; l++) {
        const int   H   = 256 >> l;
        const float inv = 1.0f / (float)(4 << l);
        const float wl  = wlv[l];
        const float ix = px * inv - 0.5f;
        const float iy = py * inv - 0.5f;
        const float x0f = floorf(ix), y0f = floorf(iy);
        const int   x0 = (int)x0f,    y0 = (int)y0f;
        const float fx1 = ix - x0f, fx0 = 1.f - fx1;
        const float fy1 = iy - y0f, fy0 = 1.f - fy1;
        const bool xi0 = (x0 >= 0) & (x0 < H);
        const bool xi1 = (x0 + 1 >= 0) & (x0 + 1 < H);
        const bool yi0 = (y0 >= 0) & (y0 < H);
        const bool yi1 = (y0 + 1 >= 0) & (y0 + 1 < H);
        const int xc0 = min(max(x0, 0), H - 1);
        const int xc1 = min(max(x0 + 1, 0), H - 1);
        const int yc0 = min(max(y0, 0), H - 1);
        const int yc1 = min(max(y0 + 1, 0), H - 1);
        const float m00 = (xi0 & yi0) ? wl * fx0 * fy0 : 0.f;
        const float m10 = (xi1 & yi0) ? wl * fx1 * fy0 : 0.f;
        const float m01 = (xi0 & yi1) ? wl * fx0 * fy1 : 0.f;
        const float m11 = (xi1 & yi1) ? wl * fx1 * fy1 : 0.f;

        const unsigned short* base = vals[l] + (size_t)b * H * H * 256 + cbase;
        const int ry0 = yc0 * H, ry1 = yc1 * H;
        const uint4 d00 = *(const uint4*)(base + (size_t)(ry0 + xc0) * 256);
        const uint4 d10 = *(const uint4*)(base + (size_t)(ry0 + xc1) * 256);
        const uint4 d01 = *(const uint4*)(base + (size_t)(ry1 + xc0) * 256);
        const uint4 d11 = *(const uint4*)(base + (size_t)(ry1 + xc1) * 256);

        const uint4 dv[4] = { d00, d10, d01, d11 };
        const float mv[4] = { m00, m10, m01, m11 };
        #pragma unroll
        for (int tap = 0; tap < 4; tap++) {
            const unsigned int du[4] = { dv[tap].x, dv[tap].y, dv[tap].z, dv[tap].w };
            const float m = mv[tap];
            #pragma unroll
            for (int i = 0; i < 4; i++) {
                union { unsigned int u; float f; } lo, hi;
                lo.u = du[i] << 16;
                hi.u = du[i] & 0xffff0000u;
                acc[2 * i]     = fmaf(m, lo.f, acc[2 * i]);
                acc[2 * i + 1] = fmaf(m, hi.f, acc[2 * i + 1]);
            }
        }
    }

    const float* caf = qd + 768 + cbase;
    const float4 ca0 = *(const float4*)caf;
    const float4 ca1 = *(const float4*)(caf + 4);
    const float cav[8] = { ca0.x, ca0.y, ca0.z, ca0.w, ca1.x, ca1.y, ca1.z, ca1.w };
    uint4 o;
    unsigned int* op = (unsigned int*)&o;
    #pragma unroll
    for (int i = 0; i < 4; i++) {
        const unsigned int lo = f2bf(acc[2 * i] * cav[2 * i]);
        const unsigned int hi = f2bf(acc[2 * i + 1] * cav[2 * i + 1]);
        op[i] = lo | (hi << 16);
    }
    *(uint4*)(X + (size_t)q * KDIM + pb * 64 + lane * 8) = o;
}

// ---------------------------------------------------------------------------
// Kernel 3: part[z] = X(MPAD,8192) @ Wtb(256,8192)^T — no-LDS streaming MFMA.
// Both operands K-contiguous: per-lane dwordx4 fragment loads (16 rows x full
// 64B lines per instr), L2-served reuse (X 4x, Wtb 32x). No barriers.
// grid (32, 4, SPLITK) = 1024 blocks. X rows >= NQ hold poison: only
// pollutes part rows >= NQ, which reduce never reads.
// ---------------------------------------------------------------------------
__global__ __launch_bounds__(256) void gemm_kernel(
    const unsigned short* __restrict__ X,    // (MPAD, 8192) bf16
    const unsigned short* __restrict__ Wt,   // (256, 8192) bf16
    float* __restrict__ part)                // (SPLITK, MPAD, 256)
{
    const int m0 = blockIdx.x * 64;
    const int n0 = blockIdx.y * 64;
    const int z  = blockIdx.z;
    const int t  = threadIdx.x;
    const int w    = t >> 6;
    const int lane = t & 63;
    const int mw = (w & 1) * 32;
    const int nw = (w >> 1) * 32;
    const int quad = lane >> 4;
    const int l16  = lane & 15;

    const unsigned short* ar0 = X  + (size_t)(m0 + mw + l16) * KDIM + quad * 8;
    const unsigned short* ar1 = ar0 + (size_t)16 * KDIM;
    const unsigned short* br0 = Wt + (size_t)(n0 + nw + l16) * KDIM + quad * 8;
    const unsigned short* br1 = br0 + (size_t)16 * KDIM;

    f32x4 acc[2][2] = {};
    const int kbase = z * (KDIM / SPLITK);
    #pragma unroll 4
    for (int k = kbase; k < kbase + KDIM / SPLITK; k += 32) {
        const bf16x8 a0 = *(const bf16x8*)(ar0 + k);
        const bf16x8 a1 = *(const bf16x8*)(ar1 + k);
        const bf16x8 b0 = *(const bf16x8*)(br0 + k);
        const bf16x8 b1 = *(const bf16x8*)(br1 + k);
        acc[0][0] = __builtin_amdgcn_mfma_f32_16x16x32_bf16(a0, b0, acc[0][0], 0, 0, 0);
        acc[0][1] = __builtin_amdgcn_mfma_f32_16x16x32_bf16(a0, b1, acc[0][1], 0, 0, 0);
        acc[1][0] = __builtin_amdgcn_mfma_f32_16x16x32_bf16(a1, b0, acc[1][0], 0, 0, 0);
        acc[1][1] = __builtin_amdgcn_mfma_f32_16x16x32_bf16(a1, b1, acc[1][1], 0, 0, 0);
    }

    float* pz = part + (size_t)z * MPAD * EMB;
    #pragma unroll
    for (int i = 0; i < 2; i++)
        #pragma unroll
        for (int j = 0; j < 2; j++) {
            const int n = n0 + nw + 16 * j + l16;
            #pragma unroll
            for (int r = 0; r < 4; r++) {
                const int m = m0 + mw + 16 * i + quad * 4 + r;
                pz[(size_t)m * EMB + n] = acc[i][j][r];
            }
        }
}

// ---------------------------------------------------------------------------
// Kernel 4: out = sum_z part[z] + bias + qc   (fp32, float4)
// ---------------------------------------------------------------------------
__global__ __launch_bounds__(256) void reduce_kernel(
    const float* __restrict__ part, const float* __restrict__ qc,
    const float* __restrict__ bias, float* __restrict__ out)
{
    const int idx = blockIdx.x * 256 + threadIdx.x;
    if (idx >= NQ * 64) return;
    const int m  = idx >> 6;
    const int c4 = idx & 63;
    float4 a = ((const float4*)bias)[c4];
    const float4 qv = ((const float4*)qc)[(size_t)m * 64 + c4];
    a.x += qv.x; a.y += qv.y; a.z += qv.z; a.w += qv.w;
    #pragma unroll
    for (int z = 0; z < SPLITK; z++) {
        const float4 p = ((const float4*)part)[((size_t)z * MPAD + m) * 64 + c4];
        a.x += p.x; a.y += p.y; a.z += p.z; a.w += p.w;
    }
    ((float4*)out)[(size_t)m * 64 + c4] = a;
}

// ---------------------------------------------------------------------------
extern "C" void kernel_launch(void* const* d_in, const int* in_sizes, int n_in,
                              void* d_out, int out_size, void* d_ws, size_t ws_size,
                              hipStream_t stream) {
    (void)in_sizes; (void)n_in; (void)out_size; (void)ws_size;
    const float* v0    = (const float*)d_in[0];
    const float* v1    = (const float*)d_in[1];
    const float* v2    = (const float*)d_in[2];
    const float* v3    = (const float*)d_in[3];
    const float* qc    = (const float*)d_in[4];
    const float* xyzrt = (const float*)d_in[5];
    const float* Woff  = (const float*)d_in[7];
    const float* boff  = (const float*)d_in[8];
    const float* Wca1  = (const float*)d_in[9];
    const float* Wca2  = (const float*)d_in[10];
    const float* Wsa1  = (const float*)d_in[11];
    const float* Wsa2  = (const float*)d_in[12];
    const float* Wout  = (const float*)d_in[13];
    const float* bout  = (const float*)d_in[14];
    float* out = (float*)d_out;

    // ws layout (bytes):
    char* p = (char*)d_ws;
    float* qdata = (float*)p;                 p += (size_t)NQ * 1024 * 4;           //  8.19 MB
    unsigned short* Xb = (unsigned short*)p;  p += (size_t)MPAD * KDIM * 2;         // 33.55 MB
    unsigned short* vt0 = (unsigned short*)p; p += (size_t)2 * 256 * 256 * 256 * 2; // 67.1 MB
    unsigned short* vt1 = (unsigned short*)p; p += (size_t)2 * 128 * 128 * 256 * 2; // 16.8 MB
    unsigned short* vt2 = (unsigned short*)p; p += (size_t)2 * 64 * 64 * 256 * 2;   //  4.2 MB
    unsigned short* vt3 = (unsigned short*)p; p += (size_t)2 * 32 * 32 * 256 * 2;   //  1.05 MB
    unsigned short* Wtb = (unsigned short*)p; p += (size_t)EMB * KDIM * 2;          //  4.2 MB
    float* partb = (float*)p;                 p += (size_t)SPLITK * MPAD * EMB * 4; // 16.8 MB
    float* Hbuf = (float*)p;                  p += (size_t)MPAD * 512 * 4;          //  4.2 MB
    unsigned short* qcH = (unsigned short*)p; p += (size_t)MPAD * 256 * 2;          //  1.05 MB
    unsigned short* qcL = (unsigned short*)p; p += (size_t)MPAD * 256 * 2;          //  1.05 MB
    unsigned short* WHb = (unsigned short*)p; p += (size_t)512 * 256 * 2;           //  0.26 MB
    unsigned short* WLb = (unsigned short*)p;                                        //  0.26 MB

    trans_kernel<<<7328, 256, 0, stream>>>(v0, v1, v2, v3, vt0, vt1, vt2, vt3,
                                           Wout, Wtb, Woff, Wca1, Wsa1,
                                           WHb, WLb, qc, qcH, qcL);
    gemmA_kernel<<<dim3(MPAD / 64, 8), 256, 0, stream>>>(qcH, qcL, WHb, WLb, Hbuf);
    finish_kernel<<<NQ / 8, 256, 0, stream>>>(Hbuf, xyzrt, boff, Wca2, Wsa2, qdata);
    sample_kernel<<<(NQ * 128) / (4 * 8), 256, 0, stream>>>(vt0, vt1, vt2, vt3, qdata, Xb);
    gemm_kernel<<<dim3(MPAD / 64, EMB / 64, SPLITK), 256, 0, stream>>>(Xb, Wtb, partb);
    reduce_kernel<<<(NQ * 64 + 255) / 256, 256, 0, stream>>>(partb, qc, bout, out);
}

// Round 4
// 390.118 us; speedup vs baseline: 1.0117x; 1.0117x over previous
//
#include <hip/hip_runtime.h>

#define NQ    2000      // B*L
#define KDIM  8192      // G*P*ch = 4*32*64
#define EMB   256
#define MPAD  2048      // NQ padded for GEMM tiles
#define SPLITK 8

typedef __attribute__((ext_vector_type(8))) short bf16x8;
typedef __attribute__((ext_vector_type(4))) float f32x4;

__device__ __forceinline__ float sigf(float x) { return 1.0f / (1.0f + __expf(-x)); }

__device__ __forceinline__ unsigned short f2bf(float x) {
    union { float f; unsigned int u; } v; v.f = x;
    unsigned int r = v.u + 0x7fffu + ((v.u >> 16) & 1u);
    return (unsigned short)(r >> 16);
}
__device__ __forceinline__ float bf2f(unsigned short h) {
    union { unsigned int u; float f; } v; v.u = ((unsigned int)h) << 16; return v.f;
}

// ---------------------------------------------------------------------------
// Kernel T (merged): all one-time layout work in a single launch.
// Region A reverted to the r0 structure (best measured: 88.7 us). Four
// structurally different region-A variants (r0-r3) all pinned at 2.0-2.2
// TB/s: the strided-plane transpose is memory-system-bound, not shape-bound.
//   region A [0,21760):      BCHW fp32 -> BHWC bf16 transpose, 4 levels
//   region B [21760,23808):  Wout(8192,256) -> Wtb(256,8192) bf16
//   region C [23808,24320):  {Woff|Wca1|Wsa1} -> WH/WL (512,256) double-bf16
//   region D [24320,26368):  qc -> qcH/qcL (2048,256) double-bf16, zero-pad
// ---------------------------------------------------------------------------
__global__ __launch_bounds__(256) void trans_kernel(
    const float* __restrict__ v0, const float* __restrict__ v1,
    const float* __restrict__ v2, const float* __restrict__ v3,
    unsigned short* __restrict__ vt0, unsigned short* __restrict__ vt1,
    unsigned short* __restrict__ vt2, unsigned short* __restrict__ vt3,
    const float* __restrict__ Wout, unsigned short* __restrict__ Wtb,
    const float* __restrict__ Woff, const float* __restrict__ Wca1,
    const float* __restrict__ Wsa1,
    unsigned short* __restrict__ WH, unsigned short* __restrict__ WL,
    const float* __restrict__ qc,
    unsigned short* __restrict__ qcH, unsigned short* __restrict__ qcL)
{
    __shared__ float tile[64][33];
    int bid = blockIdx.x;
    const int t = threadIdx.x;

    if (bid < 21760) {
        const float* v; unsigned short* vt; int H;
        if (bid < 16384)      { v = v0; vt = vt0; H = 256; }
        else if (bid < 20480) { bid -= 16384; v = v1; vt = vt1; H = 128; }
        else if (bid < 21504) { bid -= 20480; v = v2; vt = vt2; H = 64; }
        else                  { bid -= 21504; v = v3; vt = vt3; H = 32; }
        const int y  = bid % H;            bid /= H;
        const int xt = bid % (H >> 5);     bid /= (H >> 5);
        const int ct = bid & 3;
        const int b  = bid >> 2;
        const float* src = v + ((size_t)(b * 256 + ct * 64) * H + y) * H + xt * 32;
        const int xi = t & 31;
        #pragma unroll
        for (int i = 0; i < 8; i++) {
            const int c = (t >> 5) + i * 8;
            tile[c][xi] = src[(size_t)c * H * H + xi];
        }
        __syncthreads();
        unsigned short* dst = vt + (((size_t)(b * H + y) * H + xt * 32) * 256) + ct * 64;
        const int ci = (t & 31) * 2;
        #pragma unroll
        for (int i = 0; i < 4; i++) {
            const int x2 = (t >> 5) + i * 8;
            ushort2 pk;
            pk.x = f2bf(tile[ci][x2]);
            pk.y = f2bf(tile[ci + 1][x2]);
            *(ushort2*)(dst + (size_t)x2 * 256 + ci) = pk;
        }
    } else if (bid < 23808) {
        const int local = bid - 21760;
        const int k0 = (local & 255) * 32, n0 = (local >> 8) * 32;
        float (*tl)[33] = tile;
        #pragma unroll
        for (int i = 0; i < 4; i++) {
            const int ki = (t >> 5) + i * 8;
            tl[ki][t & 31] = Wout[(size_t)(k0 + ki) * 256 + n0 + (t & 31)];
        }
        __syncthreads();
        #pragma unroll
        for (int i = 0; i < 4; i++) {
            const int ni = (t >> 5) + i * 8;
            const int ki = t & 31;
            Wtb[(size_t)(n0 + ni) * KDIM + k0 + ki] = f2bf(tl[ki][ni]);
        }
    } else if (bid < 24320) {
        const int n = bid - 23808;        // 0..511, thread = k
        float val;
        if (n < 384)      val = Woff[(size_t)t * 384 + n];
        else if (n < 448) val = Wca1[(size_t)t * 64 + (n - 384)];
        else              val = Wsa1[(size_t)t * 64 + (n - 448)];
        const unsigned short hh = f2bf(val);
        WH[(size_t)n * 256 + t] = hh;
        WL[(size_t)n * 256 + t] = f2bf(val - bf2f(hh));
    } else {
        const int q = bid - 24320;        // 0..2047
        const float val = (q < NQ) ? qc[(size_t)q * 256 + t] : 0.f;
        const unsigned short hh = f2bf(val);
        qcH[(size_t)q * 256 + t] = hh;
        qcL[(size_t)q * 256 + t] = f2bf(val - bf2f(hh));
    }
}

// ---------------------------------------------------------------------------
// Kernel A: H(2048,512) = qc(2048,256) @ [Woff|Wca1|Wsa1](256,512), fp32-ish
// accuracy via double-bf16 (3 MFMA passes: AH*BH + AH*BL + AL*BH).
// No LDS; fragments loaded directly from global (K-contiguous both sides).
// grid (32, 8), 256 thr = 4 waves, wave = 32x32 quadrant (2x2 of 16x16x32).
// ---------------------------------------------------------------------------
__global__ __launch_bounds__(256) void gemmA_kernel(
    const unsigned short* __restrict__ qcH, const unsigned short* __restrict__ qcL,
    const unsigned short* __restrict__ WH,  const unsigned short* __restrict__ WL,
    float* __restrict__ Hout)               // (2048, 512)
{
    const int m0 = blockIdx.x * 64;
    const int n0 = blockIdx.y * 64;
    const int t  = threadIdx.x;
    const int w    = t >> 6;
    const int lane = t & 63;
    const int mw = (w & 1) * 32;
    const int nw = (w >> 1) * 32;
    const int quad = lane >> 4;
    const int l16  = lane & 15;

    f32x4 acc[2][2] = {};
    #pragma unroll
    for (int pass = 0; pass < 3; pass++) {
        const unsigned short* Ap = (pass == 2) ? qcL : qcH;
        const unsigned short* Bp = (pass == 1) ? WL : WH;
        const unsigned short* ar0 = Ap + (size_t)(m0 + mw + l16) * 256 + quad * 8;
        const unsigned short* ar1 = ar0 + 16 * 256;
        const unsigned short* br0 = Bp + (size_t)(n0 + nw + l16) * 256 + quad * 8;
        const unsigned short* br1 = br0 + 16 * 256;
        #pragma unroll
        for (int k = 0; k < 256; k += 32) {
            const bf16x8 a0 = *(const bf16x8*)(ar0 + k);
            const bf16x8 a1 = *(const bf16x8*)(ar1 + k);
            const bf16x8 b0 = *(const bf16x8*)(br0 + k);
            const bf16x8 b1 = *(const bf16x8*)(br1 + k);
            acc[0][0] = __builtin_amdgcn_mfma_f32_16x16x32_bf16(a0, b0, acc[0][0], 0, 0, 0);
            acc[0][1] = __builtin_amdgcn_mfma_f32_16x16x32_bf16(a0, b1, acc[0][1], 0, 0, 0);
            acc[1][0] = __builtin_amdgcn_mfma_f32_16x16x32_bf16(a1, b0, acc[1][0], 0, 0, 0);
            acc[1][1] = __builtin_amdgcn_mfma_f32_16x16x32_bf16(a1, b1, acc[1][1], 0, 0, 0);
        }
    }
    #pragma unroll
    for (int i = 0; i < 2; i++)
        #pragma unroll
        for (int j = 0; j < 2; j++) {
            const int n = n0 + nw + 16 * j + l16;
            #pragma unroll
            for (int r = 0; r < 4; r++) {
                const int m = m0 + mw + 16 * i + quad * 4 + r;
                Hout[(size_t)m * 512 + n] = acc[i][j][r];
            }
        }
}

// ---------------------------------------------------------------------------
// Kernel F: finish — per 8-query block: ca/sa second-layer dots + sigmoid +
// sampling geometry. Reads H(2048,512): [0,384)=offsets(+boff here),
// [384,448)=ca hidden (relu), [448,512)=sa hidden (relu).
// qdata per query (1024 f): [0,128) px | [128,256) py | [256,768) w[p][4] |
// [768,1024) ca.
// ---------------------------------------------------------------------------
__global__ __launch_bounds__(256) void finish_kernel(
    const float* __restrict__ Hbuf, const float* __restrict__ xyzrt,
    const float* __restrict__ boff,
    const float* __restrict__ Wca2, const float* __restrict__ Wsa2,
    float* __restrict__ qdata)
{
    const int q0 = blockIdx.x * 8;
    const int t  = threadIdx.x;
    __shared__ float hca[8][64];
    __shared__ float hsa[8][64];
    __shared__ float sas[8][128];

    for (int i = t; i < 1024; i += 256) {
        const int q = i >> 7, j = i & 127;
        const float v = fmaxf(Hbuf[(size_t)(q0 + q) * 512 + 384 + j], 0.f);
        if (j < 64) hca[q][j] = v; else hsa[q][j - 64] = v;
    }
    __syncthreads();

    {   // ca: channel c = t, all 8 queries
        float acc[8] = {};
        for (int j = 0; j < 64; j++) {
            const float wv = Wca2[(size_t)j * 256 + t];
            #pragma unroll
            for (int q = 0; q < 8; q++) acc[q] = fmaf(hca[q][j], wv, acc[q]);
        }
        #pragma unroll
        for (int q = 0; q < 8; q++)
            qdata[(size_t)(q0 + q) * 1024 + 768 + t] = sigf(acc[q]);
    }
    {   // sa: c = t&127, 4 queries per thread
        const int c  = t & 127;
        const int qb = (t >> 7) * 4;
        float acc[4] = {};
        for (int j = 0; j < 64; j++) {
            const float wv = Wsa2[(size_t)j * 128 + c];
            #pragma unroll
            for (int qq = 0; qq < 4; qq++) acc[qq] = fmaf(hsa[qb + qq][j], wv, acc[qq]);
        }
        #pragma unroll
        for (int qq = 0; qq < 4; qq++) sas[qb + qq][c] = sigf(acc[qq]);
    }
    __syncthreads();

    {   // geometry: p = t&127, 4 queries per thread
        const int p  = t & 127;
        const int qb = (t >> 7) * 4;
        #pragma unroll
        for (int qq = 0; qq < 4; qq++) {
            const int q = qb + qq;
            const float* hrow = Hbuf + (size_t)(q0 + q) * 512 + p * 3;
            const float o0 = hrow[0] + boff[p * 3 + 0];
            const float o1 = hrow[1] + boff[p * 3 + 1];
            const float o2 = hrow[2] + boff[p * 3 + 2];
            const float* xr = xyzrt + (size_t)(q0 + q) * 5;
            const float x = xr[0], y = xr[1], z = xr[2], r = xr[3], th = xr[4];
            const float sc  = exp2f(z);
            const float rw  = sc * exp2f(-0.5f * r);
            const float rh  = sc * exp2f( 0.5f * r);
            const float cth = __cosf(th), sth = __sinf(th);
            const float ox = o0 * rw;
            const float oy = o1 * rh;
            float* qd = qdata + (size_t)(q0 + q) * 1024;
            qd[p]       = x + cth * ox - sth * oy;
            qd[128 + p] = y + sth * ox + cth * oy;
            const float sz = z + o2;
            const float sa = sas[q][p];
            #pragma unroll
            for (int l = 0; l < 4; l++) {
                const float d = sz - (float)(2 + l);
                qd[256 + p * 4 + l] = sigf(-0.5f * d * d) * sa;
            }
        }
    }
}

// ---------------------------------------------------------------------------
// Kernel 2: vectorized multi-level bilinear sampling from BHWC bf16.
// One wave = 8 points x 64 ch; lane = (pt = lane>>3, c8 = (lane&7)*8).
// Restructured for max MLP: all geometry -> ALL 16 uint4 gathers issued ->
// all FMAs. Identical FP order (s = l*4+tap), bit-identical output.
// ---------------------------------------------------------------------------
__global__ __launch_bounds__(256) void sample_kernel(
    const unsigned short* __restrict__ v0, const unsigned short* __restrict__ v1,
    const unsigned short* __restrict__ v2, const unsigned short* __restrict__ v3,
    const float* __restrict__ qdata,
    unsigned short* __restrict__ X)
{
    const int wid  = blockIdx.x * 4 + (threadIdx.x >> 6);
    const int lane = threadIdx.x & 63;
    const int q  = wid >> 4;
    const int pb = (wid & 15) * 8;
    const int pt = lane >> 3;
    const int gp = pb + pt;
    const int g  = gp >> 5;
    const int c8 = (lane & 7) * 8;
    const int b  = (q >= 1000) ? 1 : 0;

    const float* qd = qdata + (size_t)q * 1024;
    const float px = qd[gp];
    const float py = qd[128 + gp];
    const float4 wl4 = *(const float4*)(qd + 256 + gp * 4);
    const float wlv[4] = { wl4.x, wl4.y, wl4.z, wl4.w };

    const unsigned short* vals[4] = { v0, v1, v2, v3 };
    const int cbase = g * 64 + c8;

    uint4 dv[16];
    float mv[16];
    #pragma unroll
    for (int l = 0; l < 4; l++) {
        const int   H   = 256 >> l;
        const float inv = 1.0f / (float)(4 << l);
        const float wl  = wlv[l];
        const float ix = px * inv - 0.5f;
        const float iy = py * inv - 0.5f;
        const float x0f = floorf(ix), y0f = floorf(iy);
        const int   x0 = (int)x0f,    y0 = (int)y0f;
        const float fx1 = ix - x0f, fx0 = 1.f - fx1;
        const float fy1 = iy - y0f, fy0 = 1.f - fy1;
        const bool xi0 = (x0 >= 0) & (x0 < H);
        const bool xi1 = (x0 + 1 >= 0) & (x0 + 1 < H);
        const bool yi0 = (y0 >= 0) & (y0 < H);
        const bool yi1 = (y0 + 1 >= 0) & (y0 + 1 < H);
        const int xc0 = min(max(x0, 0), H - 1);
        const int xc1 = min(max(x0 + 1, 0), H - 1);
        const int yc0 = min(max(y0, 0), H - 1);
        const int yc1 = min(max(y0 + 1, 0), H - 1);
        mv[l * 4 + 0] = (xi0 & yi0) ? wl * fx0 * fy0 : 0.f;
        mv[l * 4 + 1] = (xi1 & yi0) ? wl * fx1 * fy0 : 0.f;
        mv[l * 4 + 2] = (xi0 & yi1) ? wl * fx0 * fy1 : 0.f;
        mv[l * 4 + 3] = (xi1 & yi1) ? wl * fx1 * fy1 : 0.f;

        const unsigned short* base = vals[l] + (size_t)b * H * H * 256 + cbase;
        const int ry0 = yc0 * H, ry1 = yc1 * H;
        dv[l * 4 + 0] = *(const uint4*)(base + (size_t)(ry0 + xc0) * 256);
        dv[l * 4 + 1] = *(const uint4*)(base + (size_t)(ry0 + xc1) * 256);
        dv[l * 4 + 2] = *(const uint4*)(base + (size_t)(ry1 + xc0) * 256);
        dv[l * 4 + 3] = *(const uint4*)(base + (size_t)(ry1 + xc1) * 256);
    }

    float acc[8] = {};
    #pragma unroll
    for (int s = 0; s < 16; s++) {
        const unsigned int du[4] = { dv[s].x, dv[s].y, dv[s].z, dv[s].w };
        const float m = mv[s];
        #pragma unroll
        for (int i = 0; i < 4; i++) {
            union { unsigned int u; float f; } lo, hi;
            lo.u = du[i] << 16;
            hi.u = du[i] & 0xffff0000u;
            acc[2 * i]     = fmaf(m, lo.f, acc[2 * i]);
            acc[2 * i + 1] = fmaf(m, hi.f, acc[2 * i + 1]);
        }
    }

    const float* caf = qd + 768 + cbase;
    const float4 ca0 = *(const float4*)caf;
    const float4 ca1 = *(const float4*)(caf + 4);
    const float cav[8] = { ca0.x, ca0.y, ca0.z, ca0.w, ca1.x, ca1.y, ca1.z, ca1.w };
    uint4 o;
    unsigned int* op = (unsigned int*)&o;
    #pragma unroll
    for (int i = 0; i < 4; i++) {
        const unsigned int lo = f2bf(acc[2 * i] * cav[2 * i]);
        const unsigned int hi = f2bf(acc[2 * i + 1] * cav[2 * i + 1]);
        op[i] = lo | (hi << 16);
    }
    *(uint4*)(X + (size_t)q * KDIM + pb * 64 + lane * 8) = o;
}

// ---------------------------------------------------------------------------
// Kernel 3: part[z] = X(MPAD,8192) @ Wtb(256,8192)^T — no-LDS streaming MFMA.
// Both operands K-contiguous: per-lane dwordx4 fragment loads (16 rows x full
// 64B lines per instr), L2-served reuse (X 4x, Wtb 32x). No barriers.
// grid (32, 4, SPLITK) = 1024 blocks. X rows >= NQ hold poison: only
// pollutes part rows >= NQ, which reduce never reads.
// ---------------------------------------------------------------------------
__global__ __launch_bounds__(256) void gemm_kernel(
    const unsigned short* __restrict__ X,    // (MPAD, 8192) bf16
    const unsigned short* __restrict__ Wt,   // (256, 8192) bf16
    float* __restrict__ part)                // (SPLITK, MPAD, 256)
{
    const int m0 = blockIdx.x * 64;
    const int n0 = blockIdx.y * 64;
    const int z  = blockIdx.z;
    const int t  = threadIdx.x;
    const int w    = t >> 6;
    const int lane = t & 63;
    const int mw = (w & 1) * 32;
    const int nw = (w >> 1) * 32;
    const int quad = lane >> 4;
    const int l16  = lane & 15;

    const unsigned short* ar0 = X  + (size_t)(m0 + mw + l16) * KDIM + quad * 8;
    const unsigned short* ar1 = ar0 + (size_t)16 * KDIM;
    const unsigned short* br0 = Wt + (size_t)(n0 + nw + l16) * KDIM + quad * 8;
    const unsigned short* br1 = br0 + (size_t)16 * KDIM;

    f32x4 acc[2][2] = {};
    const int kbase = z * (KDIM / SPLITK);
    #pragma unroll 4
    for (int k = kbase; k < kbase + KDIM / SPLITK; k += 32) {
        const bf16x8 a0 = *(const bf16x8*)(ar0 + k);
        const bf16x8 a1 = *(const bf16x8*)(ar1 + k);
        const bf16x8 b0 = *(const bf16x8*)(br0 + k);
        const bf16x8 b1 = *(const bf16x8*)(br1 + k);
        acc[0][0] = __builtin_amdgcn_mfma_f32_16x16x32_bf16(a0, b0, acc[0][0], 0, 0, 0);
        acc[0][1] = __builtin_amdgcn_mfma_f32_16x16x32_bf16(a0, b1, acc[0][1], 0, 0, 0);
        acc[1][0] = __builtin_amdgcn_mfma_f32_16x16x32_bf16(a1, b0, acc[1][0], 0, 0, 0);
        acc[1][1] = __builtin_amdgcn_mfma_f32_16x16x32_bf16(a1, b1, acc[1][1], 0, 0, 0);
    }

    float* pz = part + (size_t)z * MPAD * EMB;
    #pragma unroll
    for (int i = 0; i < 2; i++)
        #pragma unroll
        for (int j = 0; j < 2; j++) {
            const int n = n0 + nw + 16 * j + l16;
            #pragma unroll
            for (int r = 0; r < 4; r++) {
                const int m = m0 + mw + 16 * i + quad * 4 + r;
                pz[(size_t)m * EMB + n] = acc[i][j][r];
            }
        }
}

// ---------------------------------------------------------------------------
// Kernel 4: out = sum_z part[z] + bias + qc   (fp32, float4)
// ---------------------------------------------------------------------------
__global__ __launch_bounds__(256) void reduce_kernel(
    const float* __restrict__ part, const float* __restrict__ qc,
    const float* __restrict__ bias, float* __restrict__ out)
{
    const int idx = blockIdx.x * 256 + threadIdx.x;
    if (idx >= NQ * 64) return;
    const int m  = idx >> 6;
    const int c4 = idx & 63;
    float4 a = ((const float4*)bias)[c4];
    const float4 qv = ((const float4*)qc)[(size_t)m * 64 + c4];
    a.x += qv.x; a.y += qv.y; a.z += qv.z; a.w += qv.w;
    #pragma unroll
    for (int z = 0; z < SPLITK; z++) {
        const float4 p = ((const float4*)part)[((size_t)z * MPAD + m) * 64 + c4];
        a.x += p.x; a.y += p.y; a.z += p.z; a.w += p.w;
    }
    ((float4*)out)[(size_t)m * 64 + c4] = a;
}

// ---------------------------------------------------------------------------
extern "C" void kernel_launch(void* const* d_in, const int* in_sizes, int n_in,
                              void* d_out, int out_size, void* d_ws, size_t ws_size,
                              hipStream_t stream) {
    (void)in_sizes; (void)n_in; (void)out_size; (void)ws_size;
    const float* v0    = (const float*)d_in[0];
    const float* v1    = (const float*)d_in[1];
    const float* v2    = (const float*)d_in[2];
    const float* v3    = (const float*)d_in[3];
    const float* qc    = (const float*)d_in[4];
    const float* xyzrt = (const float*)d_in[5];
    const float* Woff  = (const float*)d_in[7];
    const float* boff  = (const float*)d_in[8];
    const float* Wca1  = (const float*)d_in[9];
    const float* Wca2  = (const float*)d_in[10];
    const float* Wsa1  = (const float*)d_in[11];
    const float* Wsa2  = (const float*)d_in[12];
    const float* Wout  = (const float*)d_in[13];
    const float* bout  = (const float*)d_in[14];
    float* out = (float*)d_out;

    // ws layout (bytes):
    char* p = (char*)d_ws;
    float* qdata = (float*)p;                 p += (size_t)NQ * 1024 * 4;           //  8.19 MB
    unsigned short* Xb = (unsigned short*)p;  p += (size_t)MPAD * KDIM * 2;         // 33.55 MB
    unsigned short* vt0 = (unsigned short*)p; p += (size_t)2 * 256 * 256 * 256 * 2; // 67.1 MB
    unsigned short* vt1 = (unsigned short*)p; p += (size_t)2 * 128 * 128 * 256 * 2; // 16.8 MB
    unsigned short* vt2 = (unsigned short*)p; p += (size_t)2 * 64 * 64 * 256 * 2;   //  4.2 MB
    unsigned short* vt3 = (unsigned short*)p; p += (size_t)2 * 32 * 32 * 256 * 2;   //  1.05 MB
    unsigned short* Wtb = (unsigned short*)p; p += (size_t)EMB * KDIM * 2;          //  4.2 MB
    float* partb = (float*)p;                 p += (size_t)SPLITK * MPAD * EMB * 4; // 16.8 MB
    float* Hbuf = (float*)p;                  p += (size_t)MPAD * 512 * 4;          //  4.2 MB
    unsigned short* qcH = (unsigned short*)p; p += (size_t)MPAD * 256 * 2;          //  1.05 MB
    unsigned short* qcL = (unsigned short*)p; p += (size_t)MPAD * 256 * 2;          //  1.05 MB
    unsigned short* WHb = (unsigned short*)p; p += (size_t)512 * 256 * 2;           //  0.26 MB
    unsigned short* WLb = (unsigned short*)p;                                        //  0.26 MB

    trans_kernel<<<26368, 256, 0, stream>>>(v0, v1, v2, v3, vt0, vt1, vt2, vt3,
                                            Wout, Wtb, Woff, Wca1, Wsa1,
                                            WHb, WLb, qc, qcH, qcL);
    gemmA_kernel<<<dim3(MPAD / 64, 8), 256, 0, stream>>>(qcH, qcL, WHb, WLb, Hbuf);
    finish_kernel<<<NQ / 8, 256, 0, stream>>>(Hbuf, xyzrt, boff, Wca2, Wsa2, qdata);
    sample_kernel<<<(NQ * 128) / (4 * 8), 256, 0, stream>>>(vt0, vt1, vt2, vt3, qdata, Xb);
    gemm_kernel<<<dim3(MPAD / 64, EMB / 64, SPLITK), 256, 0, stream>>>(Xb, Wtb, partb);
    reduce_kernel<<<(NQ * 64 + 255) / 256, 256, 0, stream>>>(partb, qc, bout, out);
}

// Round 5
// 380.273 us; speedup vs baseline: 1.0379x; 1.0259x over previous
//
#include <hip/hip_runtime.h>

#define NQ    2000      // B*L
#define KDIM  8192      // G*P*ch = 4*32*64
#define EMB   256
#define MPAD  2048      // row padding kept for part buffer layout
#define NH    4         // heads = split-K partials

typedef __attribute__((ext_vector_type(8))) short bf16x8;
typedef __attribute__((ext_vector_type(4))) float f32x4;

__device__ __forceinline__ float sigf(float x) { return 1.0f / (1.0f + __expf(-x)); }

__device__ __forceinline__ unsigned short f2bf(float x) {
    union { float f; unsigned int u; } v; v.f = x;
    unsigned int r = v.u + 0x7fffu + ((v.u >> 16) & 1u);
    return (unsigned short)(r >> 16);
}
__device__ __forceinline__ float bf2f(unsigned short h) {
    union { unsigned int u; float f; } v; v.u = ((unsigned int)h) << 16; return v.f;
}

// ---------------------------------------------------------------------------
// Kernel T (merged): all one-time layout work in a single launch.
// Region A = r0 structure (measured floor ~88.7 us; four structurally
// different variants all pinned at 2.0-2.2 TB/s -> memory-system-bound).
//   region A [0,21760):      BCHW fp32 -> BHWC bf16 transpose, 4 levels
//   region B [21760,23808):  Wout(8192,256) -> Wtb(256,8192) bf16
//   region C [23808,24320):  {Woff|Wca1|Wsa1} -> WH/WL (512,256) double-bf16
//   region D [24320,26368):  qc -> qcH/qcL (2048,256) double-bf16, zero-pad
// ---------------------------------------------------------------------------
__global__ __launch_bounds__(256) void trans_kernel(
    const float* __restrict__ v0, const float* __restrict__ v1,
    const float* __restrict__ v2, const float* __restrict__ v3,
    unsigned short* __restrict__ vt0, unsigned short* __restrict__ vt1,
    unsigned short* __restrict__ vt2, unsigned short* __restrict__ vt3,
    const float* __restrict__ Wout, unsigned short* __restrict__ Wtb,
    const float* __restrict__ Woff, const float* __restrict__ Wca1,
    const float* __restrict__ Wsa1,
    unsigned short* __restrict__ WH, unsigned short* __restrict__ WL,
    const float* __restrict__ qc,
    unsigned short* __restrict__ qcH, unsigned short* __restrict__ qcL)
{
    __shared__ float tile[64][33];
    int bid = blockIdx.x;
    const int t = threadIdx.x;

    if (bid < 21760) {
        const float* v; unsigned short* vt; int H;
        if (bid < 16384)      { v = v0; vt = vt0; H = 256; }
        else if (bid < 20480) { bid -= 16384; v = v1; vt = vt1; H = 128; }
        else if (bid < 21504) { bid -= 20480; v = v2; vt = vt2; H = 64; }
        else                  { bid -= 21504; v = v3; vt = vt3; H = 32; }
        const int y  = bid % H;            bid /= H;
        const int xt = bid % (H >> 5);     bid /= (H >> 5);
        const int ct = bid & 3;
        const int b  = bid >> 2;
        const float* src = v + ((size_t)(b * 256 + ct * 64) * H + y) * H + xt * 32;
        const int xi = t & 31;
        #pragma unroll
        for (int i = 0; i < 8; i++) {
            const int c = (t >> 5) + i * 8;
            tile[c][xi] = src[(size_t)c * H * H + xi];
        }
        __syncthreads();
        unsigned short* dst = vt + (((size_t)(b * H + y) * H + xt * 32) * 256) + ct * 64;
        const int ci = (t & 31) * 2;
        #pragma unroll
        for (int i = 0; i < 4; i++) {
            const int x2 = (t >> 5) + i * 8;
            ushort2 pk;
            pk.x = f2bf(tile[ci][x2]);
            pk.y = f2bf(tile[ci + 1][x2]);
            *(ushort2*)(dst + (size_t)x2 * 256 + ci) = pk;
        }
    } else if (bid < 23808) {
        const int local = bid - 21760;
        const int k0 = (local & 255) * 32, n0 = (local >> 8) * 32;
        float (*tl)[33] = tile;
        #pragma unroll
        for (int i = 0; i < 4; i++) {
            const int ki = (t >> 5) + i * 8;
            tl[ki][t & 31] = Wout[(size_t)(k0 + ki) * 256 + n0 + (t & 31)];
        }
        __syncthreads();
        #pragma unroll
        for (int i = 0; i < 4; i++) {
            const int ni = (t >> 5) + i * 8;
            const int ki = t & 31;
            Wtb[(size_t)(n0 + ni) * KDIM + k0 + ki] = f2bf(tl[ki][ni]);
        }
    } else if (bid < 24320) {
        const int n = bid - 23808;        // 0..511, thread = k
        float val;
        if (n < 384)      val = Woff[(size_t)t * 384 + n];
        else if (n < 448) val = Wca1[(size_t)t * 64 + (n - 384)];
        else              val = Wsa1[(size_t)t * 64 + (n - 448)];
        const unsigned short hh = f2bf(val);
        WH[(size_t)n * 256 + t] = hh;
        WL[(size_t)n * 256 + t] = f2bf(val - bf2f(hh));
    } else {
        const int q = bid - 24320;        // 0..2047
        const float val = (q < NQ) ? qc[(size_t)q * 256 + t] : 0.f;
        const unsigned short hh = f2bf(val);
        qcH[(size_t)q * 256 + t] = hh;
        qcL[(size_t)q * 256 + t] = f2bf(val - bf2f(hh));
    }
}

// ---------------------------------------------------------------------------
// Kernel A: H(2048,512) = qc(2048,256) @ [Woff|Wca1|Wsa1](256,512), fp32-ish
// accuracy via double-bf16 (3 MFMA passes: AH*BH + AH*BL + AL*BH).
// ---------------------------------------------------------------------------
__global__ __launch_bounds__(256) void gemmA_kernel(
    const unsigned short* __restrict__ qcH, const unsigned short* __restrict__ qcL,
    const unsigned short* __restrict__ WH,  const unsigned short* __restrict__ WL,
    float* __restrict__ Hout)               // (2048, 512)
{
    const int m0 = blockIdx.x * 64;
    const int n0 = blockIdx.y * 64;
    const int t  = threadIdx.x;
    const int w    = t >> 6;
    const int lane = t & 63;
    const int mw = (w & 1) * 32;
    const int nw = (w >> 1) * 32;
    const int quad = lane >> 4;
    const int l16  = lane & 15;

    f32x4 acc[2][2] = {};
    #pragma unroll
    for (int pass = 0; pass < 3; pass++) {
        const unsigned short* Ap = (pass == 2) ? qcL : qcH;
        const unsigned short* Bp = (pass == 1) ? WL : WH;
        const unsigned short* ar0 = Ap + (size_t)(m0 + mw + l16) * 256 + quad * 8;
        const unsigned short* ar1 = ar0 + 16 * 256;
        const unsigned short* br0 = Bp + (size_t)(n0 + nw + l16) * 256 + quad * 8;
        const unsigned short* br1 = br0 + 16 * 256;
        #pragma unroll
        for (int k = 0; k < 256; k += 32) {
            const bf16x8 a0 = *(const bf16x8*)(ar0 + k);
            const bf16x8 a1 = *(const bf16x8*)(ar1 + k);
            const bf16x8 b0 = *(const bf16x8*)(br0 + k);
            const bf16x8 b1 = *(const bf16x8*)(br1 + k);
            acc[0][0] = __builtin_amdgcn_mfma_f32_16x16x32_bf16(a0, b0, acc[0][0], 0, 0, 0);
            acc[0][1] = __builtin_amdgcn_mfma_f32_16x16x32_bf16(a0, b1, acc[0][1], 0, 0, 0);
            acc[1][0] = __builtin_amdgcn_mfma_f32_16x16x32_bf16(a1, b0, acc[1][0], 0, 0, 0);
            acc[1][1] = __builtin_amdgcn_mfma_f32_16x16x32_bf16(a1, b1, acc[1][1], 0, 0, 0);
        }
    }
    #pragma unroll
    for (int i = 0; i < 2; i++)
        #pragma unroll
        for (int j = 0; j < 2; j++) {
            const int n = n0 + nw + 16 * j + l16;
            #pragma unroll
            for (int r = 0; r < 4; r++) {
                const int m = m0 + mw + 16 * i + quad * 4 + r;
                Hout[(size_t)m * 512 + n] = acc[i][j][r];
            }
        }
}

// ---------------------------------------------------------------------------
// Kernel F: finish — per 8-query block: ca/sa second-layer dots + sigmoid +
// sampling geometry -> qdata.
// ---------------------------------------------------------------------------
__global__ __launch_bounds__(256) void finish_kernel(
    const float* __restrict__ Hbuf, const float* __restrict__ xyzrt,
    const float* __restrict__ boff,
    const float* __restrict__ Wca2, const float* __restrict__ Wsa2,
    float* __restrict__ qdata)
{
    const int q0 = blockIdx.x * 8;
    const int t  = threadIdx.x;
    __shared__ float hca[8][64];
    __shared__ float hsa[8][64];
    __shared__ float sas[8][128];

    for (int i = t; i < 1024; i += 256) {
        const int q = i >> 7, j = i & 127;
        const float v = fmaxf(Hbuf[(size_t)(q0 + q) * 512 + 384 + j], 0.f);
        if (j < 64) hca[q][j] = v; else hsa[q][j - 64] = v;
    }
    __syncthreads();

    {   // ca: channel c = t, all 8 queries
        float acc[8] = {};
        for (int j = 0; j < 64; j++) {
            const float wv = Wca2[(size_t)j * 256 + t];
            #pragma unroll
            for (int q = 0; q < 8; q++) acc[q] = fmaf(hca[q][j], wv, acc[q]);
        }
        #pragma unroll
        for (int q = 0; q < 8; q++)
            qdata[(size_t)(q0 + q) * 1024 + 768 + t] = sigf(acc[q]);
    }
    {   // sa: c = t&127, 4 queries per thread
        const int c  = t & 127;
        const int qb = (t >> 7) * 4;
        float acc[4] = {};
        for (int j = 0; j < 64; j++) {
            const float wv = Wsa2[(size_t)j * 128 + c];
            #pragma unroll
            for (int qq = 0; qq < 4; qq++) acc[qq] = fmaf(hsa[qb + qq][j], wv, acc[qq]);
        }
        #pragma unroll
        for (int qq = 0; qq < 4; qq++) sas[qb + qq][c] = sigf(acc[qq]);
    }
    __syncthreads();

    {   // geometry: p = t&127, 4 queries per thread
        const int p  = t & 127;
        const int qb = (t >> 7) * 4;
        #pragma unroll
        for (int qq = 0; qq < 4; qq++) {
            const int q = qb + qq;
            const float* hrow = Hbuf + (size_t)(q0 + q) * 512 + p * 3;
            const float o0 = hrow[0] + boff[p * 3 + 0];
            const float o1 = hrow[1] + boff[p * 3 + 1];
            const float o2 = hrow[2] + boff[p * 3 + 2];
            const float* xr = xyzrt + (size_t)(q0 + q) * 5;
            const float x = xr[0], y = xr[1], z = xr[2], r = xr[3], th = xr[4];
            const float sc  = exp2f(z);
            const float rw  = sc * exp2f(-0.5f * r);
            const float rh  = sc * exp2f( 0.5f * r);
            const float cth = __cosf(th), sth = __sinf(th);
            const float ox = o0 * rw;
            const float oy = o1 * rh;
            float* qd = qdata + (size_t)(q0 + q) * 1024;
            qd[p]       = x + cth * ox - sth * oy;
            qd[128 + p] = y + sth * ox + cth * oy;
            const float sz = z + o2;
            const float sa = sas[q][p];
            #pragma unroll
            for (int l = 0; l < 4; l++) {
                const float d = sz - (float)(2 + l);
                qd[256 + p * 4 + l] = sigf(-0.5f * d * d) * sa;
            }
        }
    }
}

// ---------------------------------------------------------------------------
// Kernel FS (fused sample+GEMM): block = 16 queries x 1 head (K-slice 2048).
// Phase 1: sample 16q x 32p x 64ch (bit-identical math to old sample_kernel,
//   incl. ca multiply + f2bf) into 64 KB LDS A-tile. Chunk swizzle:
//   byte(q, C) = q*4096 + (C ^ (q&7))*16  (C = p*8 + ck, 16B chunks) -- the
//   4 KB q-stride is bank-aligned; without the XOR phase-2 ds_reads would be
//   16-way conflicted (G4).
// Phase 2: C(16x256) = A(16x2048) @ Wt_g^T, A from LDS, B streamed k-contig
//   (same fragment pattern as the old gemm_kernel). part[g] = head partial.
// Eliminates the X round-trip (33 MB write + 134 MB L2 re-read) and one
// kernel boundary. Grid 125 x 4 (2000 = 125*16 exactly: no pad, no guards).
// ---------------------------------------------------------------------------
__global__ __launch_bounds__(512, 4) void fused_kernel(
    const unsigned short* __restrict__ v0, const unsigned short* __restrict__ v1,
    const unsigned short* __restrict__ v2, const unsigned short* __restrict__ v3,
    const float* __restrict__ qdata,
    const unsigned short* __restrict__ Wt,   // (256, 8192) bf16
    float* __restrict__ part)                // (NH, MPAD, 256)
{
    __shared__ __align__(16) unsigned char Alds[16 * 4096];   // 64 KB
    const int q0 = blockIdx.x * 16;
    const int g  = blockIdx.y;
    const int t  = threadIdx.x;
    const int w    = t >> 6;
    const int lane = t & 63;

    const unsigned short* vals[4] = { v0, v1, v2, v3 };

    // ---------------- phase 1: sample into LDS ----------------
    {
        const int pt = lane >> 3;           // point within wave (0..7)
        const int ck = lane & 7;            // 16B chunk within point (8 ch)
        const int p  = (w & 3) * 8 + pt;    // point within head (0..31)
        const int cbase = g * 64 + ck * 8;
        const int gp = g * 32 + p;

        #pragma unroll
        for (int r = 0; r < 8; r++) {
            const int qloc = r * 2 + (w >> 2);
            const int q = q0 + qloc;
            const int b = (q >= 1000) ? 1 : 0;
            const float* qd = qdata + (size_t)q * 1024;
            const float px = qd[gp];
            const float py = qd[128 + gp];
            const float4 wl4 = *(const float4*)(qd + 256 + gp * 4);
            const float wlv[4] = { wl4.x, wl4.y, wl4.z, wl4.w };

            float acc[8] = {};
            #pragma unroll
            for (int half = 0; half < 2; half++) {
                uint4 dv[8];
                float mv[8];
                #pragma unroll
                for (int li = 0; li < 2; li++) {
                    const int l = half * 2 + li;
                    const int   H   = 256 >> l;
                    const float inv = 1.0f / (float)(4 << l);
                    const float wl  = wlv[l];
                    const float ix = px * inv - 0.5f;
                    const float iy = py * inv - 0.5f;
                    const float x0f = floorf(ix), y0f = floorf(iy);
                    const int   x0 = (int)x0f,    y0 = (int)y0f;
                    const float fx1 = ix - x0f, fx0 = 1.f - fx1;
                    const float fy1 = iy - y0f, fy0 = 1.f - fy1;
                    const bool xi0 = (x0 >= 0) & (x0 < H);
                    const bool xi1 = (x0 + 1 >= 0) & (x0 + 1 < H);
                    const bool yi0 = (y0 >= 0) & (y0 < H);
                    const bool yi1 = (y0 + 1 >= 0) & (y0 + 1 < H);
                    const int xc0 = min(max(x0, 0), H - 1);
                    const int xc1 = min(max(x0 + 1, 0), H - 1);
                    const int yc0 = min(max(y0, 0), H - 1);
                    const int yc1 = min(max(y0 + 1, 0), H - 1);
                    mv[li * 4 + 0] = (xi0 & yi0) ? wl * fx0 * fy0 : 0.f;
                    mv[li * 4 + 1] = (xi1 & yi0) ? wl * fx1 * fy0 : 0.f;
                    mv[li * 4 + 2] = (xi0 & yi1) ? wl * fx0 * fy1 : 0.f;
                    mv[li * 4 + 3] = (xi1 & yi1) ? wl * fx1 * fy1 : 0.f;
                    const unsigned short* base = vals[l] + (size_t)b * H * H * 256 + cbase;
                    const int ry0 = yc0 * H, ry1 = yc1 * H;
                    dv[li * 4 + 0] = *(const uint4*)(base + (size_t)(ry0 + xc0) * 256);
                    dv[li * 4 + 1] = *(const uint4*)(base + (size_t)(ry0 + xc1) * 256);
                    dv[li * 4 + 2] = *(const uint4*)(base + (size_t)(ry1 + xc0) * 256);
                    dv[li * 4 + 3] = *(const uint4*)(base + (size_t)(ry1 + xc1) * 256);
                }
                #pragma unroll
                for (int s = 0; s < 8; s++) {
                    const unsigned int du[4] = { dv[s].x, dv[s].y, dv[s].z, dv[s].w };
                    const float m = mv[s];
                    #pragma unroll
                    for (int i = 0; i < 4; i++) {
                        union { unsigned int u; float f; } lo, hi;
                        lo.u = du[i] << 16;
                        hi.u = du[i] & 0xffff0000u;
                        acc[2 * i]     = fmaf(m, lo.f, acc[2 * i]);
                        acc[2 * i + 1] = fmaf(m, hi.f, acc[2 * i + 1]);
                    }
                }
            }

            const float* caf = qd + 768 + cbase;
            const float4 ca0 = *(const float4*)caf;
            const float4 ca1 = *(const float4*)(caf + 4);
            const float cav[8] = { ca0.x, ca0.y, ca0.z, ca0.w, ca1.x, ca1.y, ca1.z, ca1.w };
            uint4 o;
            unsigned int* op = (unsigned int*)&o;
            #pragma unroll
            for (int i = 0; i < 4; i++) {
                const unsigned int lo = f2bf(acc[2 * i] * cav[2 * i]);
                const unsigned int hi = f2bf(acc[2 * i + 1] * cav[2 * i + 1]);
                op[i] = lo | (hi << 16);
            }
            const unsigned int C = (unsigned)(p * 8 + ck);
            const unsigned int byteoff = (unsigned)qloc * 4096u + ((C ^ (unsigned)(qloc & 7)) * 16u);
            *(uint4*)(Alds + byteoff) = o;
        }
    }
    __syncthreads();

    // ---------------- phase 2: MFMA ----------------
    {
        const int quad = lane >> 4;
        const int l16  = lane & 15;
        const unsigned short* br0 = Wt + (size_t)(w * 32 + l16) * KDIM + g * 2048 + quad * 8;
        const unsigned short* br1 = br0 + (size_t)16 * KDIM;
        const unsigned char* a_base = Alds + l16 * 4096;
        const unsigned int axor = (unsigned)(l16 & 7);

        f32x4 acc0 = {}, acc1 = {};
        #pragma unroll 8
        for (int kit = 0; kit < 64; kit++) {
            const bf16x8 a  = *(const bf16x8*)(a_base + (((unsigned)(kit * 4 + quad) ^ axor) * 16u));
            const bf16x8 b0 = *(const bf16x8*)(br0 + kit * 32);
            const bf16x8 b1 = *(const bf16x8*)(br1 + kit * 32);
            acc0 = __builtin_amdgcn_mfma_f32_16x16x32_bf16(a, b0, acc0, 0, 0, 0);
            acc1 = __builtin_amdgcn_mfma_f32_16x16x32_bf16(a, b1, acc1, 0, 0, 0);
        }

        float* pz = part + ((size_t)g * MPAD + q0) * EMB;
        #pragma unroll
        for (int r = 0; r < 4; r++) {
            const int m = quad * 4 + r;
            pz[(size_t)m * EMB + w * 32 + l16]      = acc0[r];
            pz[(size_t)m * EMB + w * 32 + 16 + l16] = acc1[r];
        }
    }
}

// ---------------------------------------------------------------------------
// Kernel 4: out = sum_g part[g] + bias + qc   (fp32, float4)
// ---------------------------------------------------------------------------
__global__ __launch_bounds__(256) void reduce_kernel(
    const float* __restrict__ part, const float* __restrict__ qc,
    const float* __restrict__ bias, float* __restrict__ out)
{
    const int idx = blockIdx.x * 256 + threadIdx.x;
    if (idx >= NQ * 64) return;
    const int m  = idx >> 6;
    const int c4 = idx & 63;
    float4 a = ((const float4*)bias)[c4];
    const float4 qv = ((const float4*)qc)[(size_t)m * 64 + c4];
    a.x += qv.x; a.y += qv.y; a.z += qv.z; a.w += qv.w;
    #pragma unroll
    for (int z = 0; z < NH; z++) {
        const float4 p = ((const float4*)part)[((size_t)z * MPAD + m) * 64 + c4];
        a.x += p.x; a.y += p.y; a.z += p.z; a.w += p.w;
    }
    ((float4*)out)[(size_t)m * 64 + c4] = a;
}

// ---------------------------------------------------------------------------
extern "C" void kernel_launch(void* const* d_in, const int* in_sizes, int n_in,
                              void* d_out, int out_size, void* d_ws, size_t ws_size,
                              hipStream_t stream) {
    (void)in_sizes; (void)n_in; (void)out_size; (void)ws_size;
    const float* v0    = (const float*)d_in[0];
    const float* v1    = (const float*)d_in[1];
    const float* v2    = (const float*)d_in[2];
    const float* v3    = (const float*)d_in[3];
    const float* qc    = (const float*)d_in[4];
    const float* xyzrt = (const float*)d_in[5];
    const float* Woff  = (const float*)d_in[7];
    const float* boff  = (const float*)d_in[8];
    const float* Wca1  = (const float*)d_in[9];
    const float* Wca2  = (const float*)d_in[10];
    const float* Wsa1  = (const float*)d_in[11];
    const float* Wsa2  = (const float*)d_in[12];
    const float* Wout  = (const float*)d_in[13];
    const float* bout  = (const float*)d_in[14];
    float* out = (float*)d_out;

    // ws layout (bytes):
    char* p = (char*)d_ws;
    float* qdata = (float*)p;                 p += (size_t)NQ * 1024 * 4;           //  8.19 MB
    unsigned short* Xb = (unsigned short*)p;  p += (size_t)MPAD * KDIM * 2;         // 33.55 MB (unused now)
    unsigned short* vt0 = (unsigned short*)p; p += (size_t)2 * 256 * 256 * 256 * 2; // 67.1 MB
    unsigned short* vt1 = (unsigned short*)p; p += (size_t)2 * 128 * 128 * 256 * 2; // 16.8 MB
    unsigned short* vt2 = (unsigned short*)p; p += (size_t)2 * 64 * 64 * 256 * 2;   //  4.2 MB
    unsigned short* vt3 = (unsigned short*)p; p += (size_t)2 * 32 * 32 * 256 * 2;   //  1.05 MB
    unsigned short* Wtb = (unsigned short*)p; p += (size_t)EMB * KDIM * 2;          //  4.2 MB
    float* partb = (float*)p;                 p += (size_t)8 * MPAD * EMB * 4;      // 16.8 MB (4 used)
    float* Hbuf = (float*)p;                  p += (size_t)MPAD * 512 * 4;          //  4.2 MB
    unsigned short* qcH = (unsigned short*)p; p += (size_t)MPAD * 256 * 2;          //  1.05 MB
    unsigned short* qcL = (unsigned short*)p; p += (size_t)MPAD * 256 * 2;          //  1.05 MB
    unsigned short* WHb = (unsigned short*)p; p += (size_t)512 * 256 * 2;           //  0.26 MB
    unsigned short* WLb = (unsigned short*)p;                                        //  0.26 MB
    (void)Xb;

    trans_kernel<<<26368, 256, 0, stream>>>(v0, v1, v2, v3, vt0, vt1, vt2, vt3,
                                            Wout, Wtb, Woff, Wca1, Wsa1,
                                            WHb, WLb, qc, qcH, qcL);
    gemmA_kernel<<<dim3(MPAD / 64, 8), 256, 0, stream>>>(qcH, qcL, WHb, WLb, Hbuf);
    finish_kernel<<<NQ / 8, 256, 0, stream>>>(Hbuf, xyzrt, boff, Wca2, Wsa2, qdata);
    fused_kernel<<<dim3(NQ / 16, NH), 512, 0, stream>>>(vt0, vt1, vt2, vt3, qdata, Wtb, partb);
    reduce_kernel<<<(NQ * 64 + 255) / 256, 256, 0, stream>>>(partb, qc, bout, out);
}